// Round 12
// baseline (991.479 us; speedup 1.0000x reference)
//
#include <hip/hip_runtime.h>
#include <math.h>

// AddrNet eval forward: B=524288, D_MODEL=128, HID=16, N_BINS=256, DEPTH=8.
// Round 12: same bit-exact arithmetic contract as PASSING R4-R11 (no-FMA
// separate mul/add roundings, k-ascending sums, bias-after, np-Cephes exp,
// mul-form silu, strict-> argmax). Change: FORCE VOP3P packed-f32 via inline
// asm (v_pk_mul_f32 / v_pk_add_f32; per-half IEEE RNE mul/add == scalar ops,
// so rounding is unchanged). State held as broadcast pairs hp[k]={h_k,h_k}
// (invariant maintained bitwise: both halves run identical op sequences).
// Weights stay uniform SGPR pairs (s_load stream), h in VGPR pairs.

constexpr int BATCH  = 524288;
constexpr int DM     = 128;
constexpr int H      = 16;
constexpr int NB     = 256;
constexpr int DEPTHN = 8;

constexpr int BLOCK = 256;

typedef float v2f __attribute__((ext_vector_type(2)));

// --- forced VOP3P helpers (bit-exact per-half IEEE f32, RNE) ---
__device__ __forceinline__ v2f pk_mul_sv(v2f wu, v2f hv) {   // uniform * vector
    v2f d;
    asm("v_pk_mul_f32 %0, %1, %2" : "=v"(d) : "s"(wu), "v"(hv));
    return d;
}
__device__ __forceinline__ v2f pk_add_vv(v2f a, v2f b) {
    v2f d;
    asm("v_pk_add_f32 %0, %1, %2" : "=v"(d) : "v"(a), "v"(b));
    return d;
}
__device__ __forceinline__ v2f pk_add_sv(v2f bu, v2f av) {   // uniform + vector
    v2f d;
    asm("v_pk_add_f32 %0, %1, %2" : "=v"(d) : "s"(bu), "v"(av));
    return d;
}

__device__ __forceinline__ float np_expf(float x) {
    // Replica of numpy's SIMD float32 exp (Cephes scheme). Explicit FMAs:
    // part of the verified contract since R4 — do not change.
    const float LOG2E = 1.442695040888963407f;
    const float C1    = 0.693359375f;
    const float C2    = -2.12194440e-4f;
    float q = rintf(x * LOG2E);
    float r = __builtin_fmaf(q, -C1, x);
    r = __builtin_fmaf(q, -C2, r);
    float p = 1.9875691500E-4f;
    p = __builtin_fmaf(p, r, 1.3981999507E-3f);
    p = __builtin_fmaf(p, r, 8.3334519073E-3f);
    p = __builtin_fmaf(p, r, 4.1665795894E-2f);
    p = __builtin_fmaf(p, r, 1.6666665459E-1f);
    p = __builtin_fmaf(p, r, 5.0000001201E-1f);
    p = __builtin_fmaf(p, r * r, r);
    p = p + 1.0f;
    if (x > 88.72283935546875f)      return INFINITY;
    if (x < -103.97208404541015625f) return 0.0f;
    return ldexpf(p, (int)q);
}

// ---- prep: pair-interleave weights (same as R11).
//   ws[p*32 + k*2 + h] = W_out[k][2p+h]   p in [0,128)
//   ws[4096 + q*32 + k*2 + h] = W_mlp[k][2q+h]  q in [0,8)
__global__ void addrnet_prep_kernel(const float* __restrict__ W_out,
                                    const float* __restrict__ W_mlp,
                                    float* __restrict__ ws) {
    int t = threadIdx.x;                       // 256 threads, 1 block
    for (int i = t; i < NB * H; i += 256) {
        int p = i >> 5, r = i & 31;
        int k = r >> 1, hh = r & 1;
        ws[i] = W_out[k * NB + (2 * p + hh)];
    }
    {
        int i = t;
        int q = i >> 5, r = i & 31;
        int k = r >> 1, hh = r & 1;
        ws[NB * H + i] = W_mlp[k * H + (2 * q + hh)];
    }
}

__global__ __launch_bounds__(BLOCK, 4) void addrnet_r12_kernel(
    const float* __restrict__ x,      // [B,128]
    const float* __restrict__ W_in,   // [128,16]
    const float* __restrict__ b_in,   // [16]
    const float* __restrict__ embed,  // [256,16]
    const float* __restrict__ b_mlp,  // [16]
    const float* __restrict__ b_out,  // [256]
    const float* __restrict__ ws,     // WP[128][16] v2f ++ WM[8][16] v2f
    int* __restrict__ out)            // [B,8] int32
{
#pragma clang fp contract(off)
    __shared__ __align__(16) float sEmb[NB * H];    // 16 KB, gather target

    for (int i = threadIdx.x; i < NB * H; i += BLOCK) sEmb[i] = embed[i];
    __syncthreads();

    const v2f* WP  = reinterpret_cast<const v2f*>(ws);            // [p][k]
    const v2f* WM  = reinterpret_cast<const v2f*>(ws + NB * H);   // [q][k]
    const v2f* BO2 = reinterpret_cast<const v2f*>(b_out);
    const v2f* BM2 = reinterpret_cast<const v2f*>(b_mlp);
    const v2f* BI2 = reinterpret_cast<const v2f*>(b_in);

    const int row = blockIdx.x * BLOCK + threadIdx.x;

    // ---- input layer: h packed as 8 v2f of element-pairs (R11 layout),
    //      pk-forced; separate mul+add roundings, k ascending. ----
    v2f h2[H / 2];
#pragma unroll
    for (int j = 0; j < H / 2; ++j) h2[j] = (v2f){0.0f, 0.0f};

    const float4* xr = reinterpret_cast<const float4*>(x + (size_t)row * DM);
    for (int k4 = 0; k4 < DM / 4; ++k4) {
        float4 v = xr[k4];
        v2f vx = {v.x, v.x}, vy = {v.y, v.y}, vz = {v.z, v.z}, vw = {v.w, v.w};
        const v2f* w0 = reinterpret_cast<const v2f*>(&W_in[(k4 * 4 + 0) * H]);
        const v2f* w1 = reinterpret_cast<const v2f*>(&W_in[(k4 * 4 + 1) * H]);
        const v2f* w2 = reinterpret_cast<const v2f*>(&W_in[(k4 * 4 + 2) * H]);
        const v2f* w3 = reinterpret_cast<const v2f*>(&W_in[(k4 * 4 + 3) * H]);
#pragma unroll
        for (int j = 0; j < H / 2; ++j) {
            v2f a = h2[j];
            a = pk_add_vv(a, pk_mul_sv(w0[j], vx));
            a = pk_add_vv(a, pk_mul_sv(w1[j], vy));
            a = pk_add_vv(a, pk_mul_sv(w2[j], vz));
            a = pk_add_vv(a, pk_mul_sv(w3[j], vw));
            h2[j] = a;
        }
    }
#pragma unroll
    for (int j = 0; j < H / 2; ++j) h2[j] = pk_add_sv(BI2[j], h2[j]);

    // ---- state: broadcast pairs hp[i] = {h_i, h_i} (both halves identical
    //      bit-patterns forever: they undergo identical IEEE op sequences) ----
    v2f hp[H];
#pragma unroll
    for (int j = 0; j < H / 2; ++j) {
        hp[2 * j + 0] = (v2f){h2[j].x, h2[j].x};
        hp[2 * j + 1] = (v2f){h2[j].y, h2[j].y};
    }

    int* o = out + (size_t)row * DEPTHN;

    for (int d = 0; d < DEPTHN; ++d) {
        // ---- logits: 2 bins per v2f, pk-forced chain, k ascending;
        //      argmax sequential bins (first-index ties) ----
        float best = -INFINITY;
        int bi = 0;
#pragma unroll 2
        for (int p = 0; p < NB / 2; ++p) {
            const v2f* wr = &WP[p * H];        // 16 uniform pairs, 128 B
            v2f acc = pk_mul_sv(wr[0], hp[0]);
#pragma unroll
            for (int k = 1; k < H; ++k)
                acc = pk_add_vv(acc, pk_mul_sv(wr[k], hp[k]));
            acc = pk_add_sv(BO2[p], acc);
            float a0 = acc.x, a1 = acc.y;
            bool c0 = a0 > best;
            bi   = c0 ? 2 * p : bi;
            best = c0 ? a0    : best;
            bool c1 = a1 > best;
            bi   = c1 ? 2 * p + 1 : bi;
            best = c1 ? a1        : best;
        }
        o[d] = bi;

        // ---- h = h + embed[bi]: add same scalar to both halves ----
        {
            const float4* e = reinterpret_cast<const float4*>(&sEmb[bi * H]);
#pragma unroll
            for (int q4 = 0; q4 < 4; ++q4) {
                float4 ev = e[q4];
                hp[q4 * 4 + 0].x += ev.x; hp[q4 * 4 + 0].y += ev.x;
                hp[q4 * 4 + 1].x += ev.y; hp[q4 * 4 + 1].y += ev.y;
                hp[q4 * 4 + 2].x += ev.z; hp[q4 * 4 + 2].y += ev.z;
                hp[q4 * 4 + 3].x += ev.w; hp[q4 * 4 + 3].y += ev.w;
            }
        }

        // ---- z = h @ W_mlp + b_mlp (pk chain); silu per half; rebroadcast ----
        float hn[H];
#pragma unroll
        for (int q = 0; q < H / 2; ++q) {
            const v2f* wr = &WM[q * H];
            v2f acc = pk_mul_sv(wr[0], hp[0]);
#pragma unroll
            for (int k = 1; k < H; ++k)
                acc = pk_add_vv(acc, pk_mul_sv(wr[k], hp[k]));
            acc = pk_add_sv(BM2[q], acc);
            float z0 = acc.x, z1 = acc.y;
            float e0 = np_expf(-z0);
            float s0 = 1.0f / (1.0f + e0);
            hn[2 * q + 0] = z0 * s0;
            float e1 = np_expf(-z1);
            float s1 = 1.0f / (1.0f + e1);
            hn[2 * q + 1] = z1 * s1;
        }
#pragma unroll
        for (int i = 0; i < H; ++i) hp[i] = (v2f){hn[i], hn[i]};
    }
}

extern "C" void kernel_launch(void* const* d_in, const int* in_sizes, int n_in,
                              void* d_out, int out_size, void* d_ws, size_t ws_size,
                              hipStream_t stream) {
    const float* x     = (const float*)d_in[0];
    const float* W_in  = (const float*)d_in[1];
    const float* b_in  = (const float*)d_in[2];
    const float* embed = (const float*)d_in[3];
    const float* W_mlp = (const float*)d_in[4];
    const float* b_mlp = (const float*)d_in[5];
    const float* W_out = (const float*)d_in[6];
    const float* b_out = (const float*)d_in[7];
    int* out  = (int*)d_out;
    float* ws = (float*)d_ws;          // needs (4096+256)*4 = 17.4 KB

    addrnet_prep_kernel<<<1, 256, 0, stream>>>(W_out, W_mlp, ws);

    dim3 grid(BATCH / BLOCK);          // 2048 blocks, 8192 waves
    dim3 block(BLOCK);
    addrnet_r12_kernel<<<grid, block, 0, stream>>>(x, W_in, b_in, embed,
                                                   b_mlp, b_out, ws, out);
}